// Round 6
// baseline (283.226 us; speedup 1.0000x reference)
//
#include <hip/hip_runtime.h>

// SelfAttention (B=4, C=256, H=W=64): fused projections + merged-wave flash.
// Round 9: r6/r7/r8 (94/95/114us) pinned aggregate issue at ~45% across three
// wave/block configs -> the barrier convoy structure itself is the limiter.
// This round: ZERO-SYNC k_flash. Each wave owns 32 q-rows x 128 channels and
// runs its own QK -> in-register softmax -> PV:
//  - P redistribution (lane=q D-layout -> A-operand k-layout) done in-register
//    with v_cvt_pk_bf16_f32 + shfl_xor(32) + per-half selects (no P LDS).
//  - V loads global->VGPR (lane=channel = B-operand cols directly).
//  - alpha broadcast via 128B wave-private LDS, only on max-change (exact).
//  - QK+softmax duplicated across the 2 channel-half waves (MFMA floor ~6us).
//  - split-K x2 -> 2048 fully independent waves, no barriers anywhere.
// k_prep/k_proj unchanged; k_combine adapted to the new partial layout.

#define B_ 4
#define C_ 256
#define N_ 4096
#define CQK 32
#define LOG2E 1.44269504088896340736f

typedef __attribute__((ext_vector_type(8))) short short8;
typedef __attribute__((ext_vector_type(4))) short short4v;
typedef __attribute__((ext_vector_type(4))) unsigned int uint4v;
typedef __attribute__((ext_vector_type(16))) float f32x16;
typedef __attribute__((ext_vector_type(4))) float f32x4;

__device__ __forceinline__ unsigned short f2bf(float f) {
  unsigned int u = __builtin_bit_cast(unsigned int, f);
  u = (u + 0x7fffu + ((u >> 16) & 1u)) >> 16;  // RNE
  return (unsigned short)u;
}
__device__ __forceinline__ float bf2f(unsigned short s) {
  unsigned int u = ((unsigned int)s) << 16;
  return __builtin_bit_cast(float, u);
}
__device__ __forceinline__ short f32tof16(float f) {
  const _Float16 hf = (_Float16)f;
  return __builtin_bit_cast(short, hf);
}
// pack two f32 -> two bf16 (RNE), one instruction
__device__ __forceinline__ unsigned int cvtpk(float lo, float hi) {
  unsigned int r;
  asm("v_cvt_pk_bf16_f32 %0, %1, %2" : "=v"(r) : "v"(lo), "v"(hi));
  return r;
}
__device__ __forceinline__ f32x16 mfma16(short8 a, short8 b, f32x16 c) {
  return __builtin_amdgcn_mfma_f32_32x32x16_bf16(a, b, c, 0, 0, 0);
}
// swizzled element index into bf16 LDS tiles (16B granules XORed by row)
__device__ __forceinline__ int swz64(int row, int col) {  // rows of 64 bf16
  return row * 64 + ((((col >> 3) ^ row) & 7) << 3) + (col & 7);
}

// ---------------- kernel 1: prep (x transpose+split, weight splits) ----------
__global__ __launch_bounds__(256) void k_prep(
    const float* __restrict__ x, unsigned short* __restrict__ xthi,
    unsigned short* __restrict__ xtlo,
    const float* __restrict__ Wq, const float* __restrict__ Wk,
    const float* __restrict__ Wv,
    unsigned short* __restrict__ wqh, unsigned short* __restrict__ wql,
    unsigned short* __restrict__ wkh, unsigned short* __restrict__ wkl,
    unsigned short* __restrict__ wvh, unsigned short* __restrict__ wvl) {
  __shared__ __align__(16) float tile[64 * 65];
  const int bi = blockIdx.x;
  const int t = threadIdx.x;
  if (bi < 1024) {
    const int it = bi & 63, ct = (bi >> 6) & 3, b = bi >> 8;
    const int i0 = it * 64, c0 = ct * 64;
    {
      const int i = t & 63, cb = t >> 6;
#pragma unroll
      for (int z = 0; z < 16; ++z) {
        const int c = z * 4 + cb;
        tile[i * 65 + c] = x[(b * C_ + c0 + c) * N_ + i0 + i];
      }
    }
    __syncthreads();
    {
      const int ii = t >> 2, p = t & 3;
      short8 h0, h1, l0, l1;
#pragma unroll
      for (int e = 0; e < 16; ++e) {
        const float f = tile[ii * 65 + p * 16 + e];
        const unsigned short hb = f2bf(f);
        const unsigned short lb = f2bf(f - bf2f(hb));
        if (e < 8) { h0[e] = (short)hb; l0[e] = (short)lb; }
        else       { h1[e - 8] = (short)hb; l1[e - 8] = (short)lb; }
      }
      const int base = (b * N_ + i0 + ii) * C_ + c0 + p * 16;
      *(short8*)(xthi + base) = h0;
      *(short8*)(xthi + base + 8) = h1;
      *(short8*)(xtlo + base) = l0;
      *(short8*)(xtlo + base + 8) = l1;
    }
  } else {
    const int e = (bi - 1024) * 256 + t;  // < 81920
    const float* src; unsigned short *hi, *lo; int idx;
    if (e < 8192)        { src = Wq; hi = wqh; lo = wql; idx = e; }
    else if (e < 16384)  { src = Wk; hi = wkh; lo = wkl; idx = e - 8192; }
    else                 { src = Wv; hi = wvh; lo = wvl; idx = e - 16384; }
    float f = src[idx];
    if (e < 8192) f *= LOG2E;  // log2-domain scores: fold log2(e) into Wq
    const unsigned short h = f2bf(f);
    hi[idx] = h;
    lo[idx] = f2bf(f - bf2f(h));
  }
}

// ---------------- kernel 2: fused q/k/v projection GEMM ----------------
__global__ __launch_bounds__(256) void k_proj(
    const unsigned short* __restrict__ wqh, const unsigned short* __restrict__ wql,
    const unsigned short* __restrict__ wkh, const unsigned short* __restrict__ wkl,
    const unsigned short* __restrict__ wvh, const unsigned short* __restrict__ wvl,
    const unsigned short* __restrict__ xthi, const unsigned short* __restrict__ xtlo,
    const float* __restrict__ bq, const float* __restrict__ bk,
    const float* __restrict__ bv,
    unsigned short* __restrict__ qhg, unsigned short* __restrict__ qlg,
    unsigned short* __restrict__ khg, unsigned short* __restrict__ klg,
    unsigned short* __restrict__ vg) {
  __shared__ __align__(16) char sm[33792];
  unsigned short* awh = (unsigned short*)sm;       // [64][64] W hi (swizzled)
  unsigned short* awl = awh + 4096;
  unsigned short* bxh = awl + 4096;                // [64][64] x^T hi
  unsigned short* bxl = bxh + 4096;
  float* qt = (float*)sm;                          // epilogue reuse: [64][65] f32

  const int it = blockIdx.x, ot = blockIdx.y, b = blockIdx.z;
  const int i0 = it * 64, o0 = ot * 64;
  const int t = threadIdx.x, lane = t & 63, w = t >> 6, h = lane >> 5;
  const int mb = w >> 1, nb = w & 1;
  const int srow = t >> 2, sp = t & 3;

  const int og = o0 + srow;
  const unsigned short *wh, *wl;
  if (og < 32)      { wh = wqh + og * C_;        wl = wql + og * C_; }
  else if (og < 64) { wh = wkh + (og - 32) * C_; wl = wkl + (og - 32) * C_; }
  else              { wh = wvh + (og - 64) * C_; wl = wvl + (og - 64) * C_; }
  const unsigned short* xh = xthi + (b * N_ + i0 + srow) * C_;
  const unsigned short* xl = xtlo + (b * N_ + i0 + srow) * C_;

  f32x16 acc;
#pragma unroll
  for (int e = 0; e < 16; ++e) acc[e] = 0.f;
  const int m = 32 * mb + (lane & 31);
  const int n = 32 * nb + (lane & 31);

  for (int kt = 0; kt < 4; ++kt) {
    const int cb = kt * 64 + sp * 16;
    *(short8*)&awh[swz64(srow, sp * 16)]     = *(const short8*)(wh + cb);
    *(short8*)&awh[swz64(srow, sp * 16 + 8)] = *(const short8*)(wh + cb + 8);
    *(short8*)&awl[swz64(srow, sp * 16)]     = *(const short8*)(wl + cb);
    *(short8*)&awl[swz64(srow, sp * 16 + 8)] = *(const short8*)(wl + cb + 8);
    *(short8*)&bxh[swz64(srow, sp * 16)]     = *(const short8*)(xh + cb);
    *(short8*)&bxh[swz64(srow, sp * 16 + 8)] = *(const short8*)(xh + cb + 8);
    *(short8*)&bxl[swz64(srow, sp * 16)]     = *(const short8*)(xl + cb);
    *(short8*)&bxl[swz64(srow, sp * 16 + 8)] = *(const short8*)(xl + cb + 8);
    __syncthreads();
#pragma unroll
    for (int kk = 0; kk < 4; ++kk) {
      const int kb = kk * 16 + h * 8;
      const short8 ah  = *(const short8*)&awh[swz64(m, kb)];
      const short8 al2 = *(const short8*)&awl[swz64(m, kb)];
      const short8 bh  = *(const short8*)&bxh[swz64(n, kb)];
      const short8 bl2 = *(const short8*)&bxl[swz64(n, kb)];
      acc = mfma16(ah, bh, acc);   // hi*hi
      acc = mfma16(ah, bl2, acc);  // hi*lo
      acc = mfma16(al2, bh, acc);  // lo*hi
    }
    __syncthreads();
  }

  if (ot > 0) {  // v epilogue: direct [B][C][N] bf16 store
#pragma unroll
    for (int e = 0; e < 16; ++e) {
      const int r = 32 * mb + (e & 3) + 8 * (e >> 2) + 4 * h;
      const int oc = o0 - 64 + r;
      vg[(b * C_ + oc) * N_ + i0 + n] = f2bf(acc[e] + bv[oc]);
    }
  } else {  // q/k epilogue: LDS transpose -> [B][N][32] hi/lo
#pragma unroll
    for (int e = 0; e < 16; ++e) {
      const int r = 32 * mb + (e & 3) + 8 * (e >> 2) + 4 * h;
      const float bias = (r < 32) ? bq[r] * LOG2E : bk[r - 32];
      qt[r * 65 + n] = acc[e] + bias;
    }
    __syncthreads();
    const int ii = t >> 2;
    short8 hv0, hv1, lv0, lv1;
#pragma unroll
    for (int e = 0; e < 16; ++e) {
      const float f = qt[(sp * 16 + e) * 65 + ii];
      const unsigned short hb = f2bf(f);
      const unsigned short lb = f2bf(f - bf2f(hb));
      if (e < 8) { hv0[e] = (short)hb; lv0[e] = (short)lb; }
      else       { hv1[e - 8] = (short)hb; lv1[e - 8] = (short)lb; }
    }
    if (sp < 2) {
      const int base = (b * N_ + i0 + ii) * CQK + sp * 16;
      *(short8*)(qhg + base) = hv0; *(short8*)(qhg + base + 8) = hv1;
      *(short8*)(qlg + base) = lv0; *(short8*)(qlg + base + 8) = lv1;
    } else {
      const int base = (b * N_ + i0 + ii) * CQK + sp * 16 - 32;
      *(short8*)(khg + base) = hv0; *(short8*)(khg + base + 8) = hv1;
      *(short8*)(klg + base) = lv0; *(short8*)(klg + base + 8) = lv1;
    }
  }
}

// ---------------- kernel 3: merged-wave flash attention (zero-sync) ---------
// 512 blocks x 256 thr (4 waves). xs = blk&7 = b*2+s (fixed per XCD: K/V/Q
// slice ~2.3MB L2-resident). Wave = (qw, ch): 32 q-rows x 128 channels, keys
// [s*2048, s*2048+2048) in 32 tiles of 64. No barriers; no P LDS.
// Per tile: QK (swapped, lane=q) -> in-reg softmax (log2 domain) ->
// cvt_pk + shfl_xor(32) redistribution into PV A-frags -> PV (V = B-operand
// from global, lane=channel). Defer-rescale via 128B wave-private LDS.
// Opart: [wave 2048][slot 8][lane 64][8 f16]; slot = ct*2 + (e>=8).
__global__ __launch_bounds__(256, 2) void k_flash(
    const unsigned short* __restrict__ qhg, const unsigned short* __restrict__ qlg,
    const unsigned short* __restrict__ khg, const unsigned short* __restrict__ klg,
    const unsigned short* __restrict__ vg,
    unsigned short* __restrict__ Opart, float* __restrict__ mlpart) {
  __shared__ float alphaW[4][32];  // per-wave alpha broadcast slot

  const int blk = blockIdx.x;
  const int xs = blk & 7;          // XCD-pinned (b, split)
  const int b = xs >> 1, s = xs & 1;
  const int gl = blk >> 3;         // 0..63
  const int t = threadIdx.x, lane = t & 63, w = t >> 6, h = lane >> 5;
  const int l31 = lane & 31;
  const int widx = gl * 4 + w;     // 0..255
  const int qw = widx >> 1, ch = widx & 1;
  const int srow = qw * 32 + l31;  // global q row of this lane
  const int jbase = s * 2048;

  // Q fragments (persistent): B-operand for QK, lane = q
  short8 qfh[2], qfl[2];
  {
    const unsigned short* qph = qhg + (size_t)(b * N_ + srow) * CQK + h * 8;
    const unsigned short* qpl = qlg + (size_t)(b * N_ + srow) * CQK + h * 8;
#pragma unroll
    for (int kk = 0; kk < 2; ++kk) {
      qfh[kk] = *(const short8*)(qph + kk * 16);
      qfl[kk] = *(const short8*)(qpl + kk * 16);
    }
  }
  // K fragments: A-operand for QK, lane = key-row (within 32)
  const unsigned short* kph = khg + (size_t)(b * N_ + jbase + l31) * CQK + h * 8;
  const unsigned short* kpl = klg + (size_t)(b * N_ + jbase + l31) * CQK + h * 8;
  short8 kfh[2][2], kfl[2][2];
  auto loadK = [&](int tau) {
#pragma unroll
    for (int jt = 0; jt < 2; ++jt)
#pragma unroll
      for (int kk = 0; kk < 2; ++kk) {
        kfh[jt][kk] = *(const short8*)(kph + tau * 2048 + jt * 1024 + kk * 16);
        kfl[jt][kk] = *(const short8*)(kpl + tau * 2048 + jt * 1024 + kk * 16);
      }
  };
  loadK(0);
  // V pointers: B-operand for PV, lane = channel; 4 c-tiles of 32
  const unsigned short* vsr0 =
      vg + (size_t)(b * C_ + ch * 128 + l31) * N_ + jbase + h * 8;

  f32x16 acc0, acc1, acc2, acc3;
#pragma unroll
  for (int e = 0; e < 16; ++e) {
    acc0[e] = 0.f; acc1[e] = 0.f; acc2[e] = 0.f; acc3[e] = 0.f;
  }
  float m_run = -1e30f, l_run = 0.f;

  for (int kt = 0; kt < 32; ++kt) {
    // V loads for this tile (complete under QK+softmax)
    short8 vf0[4], vf1[4], vf2[4], vf3[4];
#pragma unroll
    for (int sl = 0; sl < 4; ++sl) {
      vf0[sl] = *(const short8*)(vsr0 + (size_t)0 * 32 * N_ + kt * 64 + sl * 16);
      vf1[sl] = *(const short8*)(vsr0 + (size_t)1 * 32 * N_ + kt * 64 + sl * 16);
      vf2[sl] = *(const short8*)(vsr0 + (size_t)2 * 32 * N_ + kt * 64 + sl * 16);
      vf3[sl] = *(const short8*)(vsr0 + (size_t)3 * 32 * N_ + kt * 64 + sl * 16);
    }
    // QK: S^T tiles, lane = q, regs = j pattern (e&3)+8*(e>>2)+4h
    f32x16 s0, s1;
#pragma unroll
    for (int e = 0; e < 16; ++e) { s0[e] = 0.f; s1[e] = 0.f; }
    __builtin_amdgcn_s_setprio(1);
#pragma unroll
    for (int kk = 0; kk < 2; ++kk) {
      s0 = mfma16(kfh[0][kk], qfh[kk], s0);
      s0 = mfma16(kfh[0][kk], qfl[kk], s0);
      s0 = mfma16(kfl[0][kk], qfh[kk], s0);
      s1 = mfma16(kfh[1][kk], qfh[kk], s1);
      s1 = mfma16(kfh[1][kk], qfl[kk], s1);
      s1 = mfma16(kfl[1][kk], qfh[kk], s1);
    }
    __builtin_amdgcn_s_setprio(0);
    if (kt + 1 < 32) loadK(kt + 1);  // prefetch next K under softmax+PV
    // ---- softmax (log2 domain), lane-local + partner merge ----
    float mx8[8];
#pragma unroll
    for (int i2 = 0; i2 < 4; ++i2) {
      mx8[i2] = fmaxf(fmaxf(s0[4 * i2], s0[4 * i2 + 1]),
                      fmaxf(s0[4 * i2 + 2], s0[4 * i2 + 3]));
      mx8[4 + i2] = fmaxf(fmaxf(s1[4 * i2], s1[4 * i2 + 1]),
                          fmaxf(s1[4 * i2 + 2], s1[4 * i2 + 3]));
    }
    float mx = fmaxf(fmaxf(fmaxf(mx8[0], mx8[1]), fmaxf(mx8[2], mx8[3])),
                     fmaxf(fmaxf(mx8[4], mx8[5]), fmaxf(mx8[6], mx8[7])));
    mx = fmaxf(mx, __shfl_xor(mx, 32));
    const float mnew = fmaxf(m_run, mx);
    const unsigned long long ba = __ballot(mnew > m_run);
    const float al = __builtin_exp2f(m_run - mnew);
#pragma unroll
    for (int e = 0; e < 16; ++e) s0[e] = __builtin_exp2f(s0[e] - mnew);
#pragma unroll
    for (int e = 0; e < 16; ++e) s1[e] = __builtin_exp2f(s1[e] - mnew);
    float t8[8];
#pragma unroll
    for (int i2 = 0; i2 < 4; ++i2) {
      t8[i2] = (s0[4 * i2] + s0[4 * i2 + 1]) + (s0[4 * i2 + 2] + s0[4 * i2 + 3]);
      t8[4 + i2] = (s1[4 * i2] + s1[4 * i2 + 1]) + (s1[4 * i2 + 2] + s1[4 * i2 + 3]);
    }
    float ts = ((t8[0] + t8[1]) + (t8[2] + t8[3])) +
               ((t8[4] + t8[5]) + (t8[6] + t8[7]));
    ts += __shfl_xor(ts, 32);
    l_run = l_run * al + ts;
    m_run = mnew;
    // ---- in-register P redistribution -> PV A-frags (verified layout) ----
    short8 pa0, pa1, pa2, pa3;
    {
      unsigned int w01 = cvtpk(s0[0], s0[1]),  w23 = cvtpk(s0[2], s0[3]);
      unsigned int w45 = cvtpk(s0[4], s0[5]),  w67 = cvtpk(s0[6], s0[7]);
      unsigned int w89 = cvtpk(s0[8], s0[9]),  wab = cvtpk(s0[10], s0[11]);
      unsigned int wcd = cvtpk(s0[12], s0[13]), wef = cvtpk(s0[14], s0[15]);
      unsigned int t01 = (unsigned)__shfl_xor((int)w01, 32);
      unsigned int t23 = (unsigned)__shfl_xor((int)w23, 32);
      unsigned int t45 = (unsigned)__shfl_xor((int)w45, 32);
      unsigned int t67 = (unsigned)__shfl_xor((int)w67, 32);
      unsigned int t89 = (unsigned)__shfl_xor((int)w89, 32);
      unsigned int tab = (unsigned)__shfl_xor((int)wab, 32);
      unsigned int tcd = (unsigned)__shfl_xor((int)wcd, 32);
      unsigned int tef = (unsigned)__shfl_xor((int)wef, 32);
      uint4v uA, uB;
      uA[0] = h ? t45 : w01;  uA[1] = h ? t67 : w23;
      uA[2] = h ? w45 : t01;  uA[3] = h ? w67 : t23;
      uB[0] = h ? tcd : w89;  uB[1] = h ? tef : wab;
      uB[2] = h ? wcd : t89;  uB[3] = h ? wef : tab;
      pa0 = __builtin_bit_cast(short8, uA);
      pa1 = __builtin_bit_cast(short8, uB);
    }
    {
      unsigned int w01 = cvtpk(s1[0], s1[1]),  w23 = cvtpk(s1[2], s1[3]);
      unsigned int w45 = cvtpk(s1[4], s1[5]),  w67 = cvtpk(s1[6], s1[7]);
      unsigned int w89 = cvtpk(s1[8], s1[9]),  wab = cvtpk(s1[10], s1[11]);
      unsigned int wcd = cvtpk(s1[12], s1[13]), wef = cvtpk(s1[14], s1[15]);
      unsigned int t01 = (unsigned)__shfl_xor((int)w01, 32);
      unsigned int t23 = (unsigned)__shfl_xor((int)w23, 32);
      unsigned int t45 = (unsigned)__shfl_xor((int)w45, 32);
      unsigned int t67 = (unsigned)__shfl_xor((int)w67, 32);
      unsigned int t89 = (unsigned)__shfl_xor((int)w89, 32);
      unsigned int tab = (unsigned)__shfl_xor((int)wab, 32);
      unsigned int tcd = (unsigned)__shfl_xor((int)wcd, 32);
      unsigned int tef = (unsigned)__shfl_xor((int)wef, 32);
      uint4v uA, uB;
      uA[0] = h ? t45 : w01;  uA[1] = h ? t67 : w23;
      uA[2] = h ? w45 : t01;  uA[3] = h ? w67 : t23;
      uB[0] = h ? tcd : w89;  uB[1] = h ? tef : wab;
      uB[2] = h ? wcd : t89;  uB[3] = h ? wef : tab;
      pa2 = __builtin_bit_cast(short8, uA);
      pa3 = __builtin_bit_cast(short8, uB);
    }
    // ---- deferred rescale (exact: skipped <=> all alphas == 1) ----
    if (ba) {
      if (h == 0) alphaW[w][l31] = al;  // same-wave DS ops are in-order
#pragma unroll
      for (int eq = 0; eq < 4; ++eq) {
        const f32x4 av = *(const f32x4*)&alphaW[w][8 * eq + 4 * h];
#pragma unroll
        for (int q = 0; q < 4; ++q) {
          acc0[4 * eq + q] *= av[q];
          acc1[4 * eq + q] *= av[q];
          acc2[4 * eq + q] *= av[q];
          acc3[4 * eq + q] *= av[q];
        }
      }
    }
    // ---- PV: acc[ct] += P^T * V (D: lane=c, regs=q pattern) ----
    __builtin_amdgcn_s_setprio(1);
    acc0 = mfma16(pa0, vf0[0], acc0);
    acc0 = mfma16(pa1, vf0[1], acc0);
    acc0 = mfma16(pa2, vf0[2], acc0);
    acc0 = mfma16(pa3, vf0[3], acc0);
    acc1 = mfma16(pa0, vf1[0], acc1);
    acc1 = mfma16(pa1, vf1[1], acc1);
    acc1 = mfma16(pa2, vf1[2], acc1);
    acc1 = mfma16(pa3, vf1[3], acc1);
    acc2 = mfma16(pa0, vf2[0], acc2);
    acc2 = mfma16(pa1, vf2[1], acc2);
    acc2 = mfma16(pa2, vf2[2], acc2);
    acc2 = mfma16(pa3, vf2[3], acc2);
    acc3 = mfma16(pa0, vf3[0], acc3);
    acc3 = mfma16(pa1, vf3[1], acc3);
    acc3 = mfma16(pa2, vf3[2], acc3);
    acc3 = mfma16(pa3, vf3[3], acc3);
    __builtin_amdgcn_s_setprio(0);
  }

  // stats: identical across ch waves -> ch==0, h==0 stores
  if (ch == 0 && h == 0) {
    mlpart[((size_t)(s * 4 + b) * 4096 + srow) * 2] = m_run;
    mlpart[((size_t)(s * 4 + b) * 4096 + srow) * 2 + 1] = l_run;
  }
  // O partials: [wave][slot 8][lane 64][8 f16], slot = ct*2 + (e>=8)
  {
    const int wv = ((s * 4 + b) * 128 + qw) * 2 + ch;
    unsigned short* dst = Opart + (size_t)wv * 4096 + lane * 8;
    short8 o;
#pragma unroll
    for (int e = 0; e < 8; ++e) o[e] = f32tof16(acc0[e]);
    *(short8*)(dst + 0 * 512) = o;
#pragma unroll
    for (int e = 0; e < 8; ++e) o[e] = f32tof16(acc0[8 + e]);
    *(short8*)(dst + 1 * 512) = o;
#pragma unroll
    for (int e = 0; e < 8; ++e) o[e] = f32tof16(acc1[e]);
    *(short8*)(dst + 2 * 512) = o;
#pragma unroll
    for (int e = 0; e < 8; ++e) o[e] = f32tof16(acc1[8 + e]);
    *(short8*)(dst + 3 * 512) = o;
#pragma unroll
    for (int e = 0; e < 8; ++e) o[e] = f32tof16(acc2[e]);
    *(short8*)(dst + 4 * 512) = o;
#pragma unroll
    for (int e = 0; e < 8; ++e) o[e] = f32tof16(acc2[8 + e]);
    *(short8*)(dst + 5 * 512) = o;
#pragma unroll
    for (int e = 0; e < 8; ++e) o[e] = f32tof16(acc3[e]);
    *(short8*)(dst + 6 * 512) = o;
#pragma unroll
    for (int e = 0; e < 8; ++e) o[e] = f32tof16(acc3[8 + e]);
    *(short8*)(dst + 7 * 512) = o;
  }
}

// ---------------- kernel 4: combine split halves + residual ----------------
// For output (b,c,i): qg = q0+i; qw = qg>>5; qi = qg&31; h = (qi>>2)&1;
// hi8 = qi>>4; eo = (qi&3)+4*((qi>>3)&1); lane = (c&31)+32h; ct = (c>>5)&3;
// ch = c>>7. m's are log2-domain -> exp2.
__global__ __launch_bounds__(256) void k_combine(
    const unsigned short* __restrict__ Opart, const float* __restrict__ mlpart,
    const float* __restrict__ x, const float* __restrict__ gamma,
    float* __restrict__ out) {
  const int cb = blockIdx.x;
  const int b = cb & 3, qt_ = cb >> 2;
  const int q0 = qt_ * 64;
  const int t = threadIdx.x;
  const int i = t & 63, cg = t >> 6;
  const int qg = q0 + i;

  const float m1 = mlpart[((size_t)(0 + b) * 4096 + qg) * 2];
  const float l1 = mlpart[((size_t)(0 + b) * 4096 + qg) * 2 + 1];
  const float m2 = mlpart[((size_t)(4 + b) * 4096 + qg) * 2];
  const float l2 = mlpart[((size_t)(4 + b) * 4096 + qg) * 2 + 1];
  const float M = fmaxf(m1, m2);
  const float w1 = __builtin_exp2f(m1 - M), w2 = __builtin_exp2f(m2 - M);
  const float inv = gamma[0] / (w1 * l1 + w2 * l2);
  const float s1 = w1 * inv, s2 = w2 * inv;

  const int qw = qg >> 5, qi = qg & 31;
  const int h = (qi >> 2) & 1;
  const int hi8 = qi >> 4;
  const int eo = (qi & 3) + 4 * ((qi >> 3) & 1);
#pragma unroll 4
  for (int c = cg; c < C_; c += 4) {
    const int ch = c >> 7, ct = (c >> 5) & 3, ln = (c & 31) + 32 * h;
    const size_t sub = (size_t)(ct * 2 + hi8) * 512 + ln * 8 + eo;
    const size_t o1 =
        (size_t)(((0 + b) * 128 + qw) * 2 + ch) * 4096 + sub;
    const size_t o2 =
        (size_t)(((4 + b) * 128 + qw) * 2 + ch) * 4096 + sub;
    const float v1 = (float)__builtin_bit_cast(_Float16, Opart[o1]);
    const float v2 = (float)__builtin_bit_cast(_Float16, Opart[o2]);
    const int g = (b * C_ + c) * N_ + qg;
    out[g] = s1 * v1 + s2 * v2 + x[g];
  }
}

// ---------------- launch ----------------
extern "C" void kernel_launch(void* const* d_in, const int* in_sizes, int n_in,
                              void* d_out, int out_size, void* d_ws, size_t ws_size,
                              hipStream_t stream) {
  const float* x     = (const float*)d_in[0];
  const float* Wq    = (const float*)d_in[1];
  const float* bq    = (const float*)d_in[2];
  const float* Wk    = (const float*)d_in[3];
  const float* bk    = (const float*)d_in[4];
  const float* Wv    = (const float*)d_in[5];
  const float* bv    = (const float*)d_in[6];
  const float* gamma = (const float*)d_in[7];
  float* out = (float*)d_out;
  (void)in_sizes; (void)n_in; (void)out_size; (void)ws_size;

  char* ws = (char*)d_ws;
  size_t off = 0;
  auto carve = [&](size_t bytes) -> char* {
    char* p = ws + off;
    off += (bytes + 255) & ~(size_t)255;
    return p;
  };
  unsigned short* xthi = (unsigned short*)carve((size_t)B_ * N_ * C_ * 2);
  unsigned short* xtlo = (unsigned short*)carve((size_t)B_ * N_ * C_ * 2);
  unsigned short* wqh  = (unsigned short*)carve(32 * 256 * 2);
  unsigned short* wql  = (unsigned short*)carve(32 * 256 * 2);
  unsigned short* wkh  = (unsigned short*)carve(32 * 256 * 2);
  unsigned short* wkl  = (unsigned short*)carve(32 * 256 * 2);
  unsigned short* wvh  = (unsigned short*)carve(256 * 256 * 2);
  unsigned short* wvl  = (unsigned short*)carve(256 * 256 * 2);
  unsigned short* qhg  = (unsigned short*)carve((size_t)B_ * N_ * CQK * 2);
  unsigned short* qlg  = (unsigned short*)carve((size_t)B_ * N_ * CQK * 2);
  unsigned short* khg  = (unsigned short*)carve((size_t)B_ * N_ * CQK * 2);
  unsigned short* klg  = (unsigned short*)carve((size_t)B_ * N_ * CQK * 2);
  unsigned short* vg   = (unsigned short*)carve((size_t)B_ * C_ * N_ * 2);
  unsigned short* Opart = (unsigned short*)carve((size_t)2048 * 4096 * 2);  // f16
  float* mlpart = (float*)carve((size_t)8 * 4096 * 2 * 4);

  k_prep<<<1344, 256, 0, stream>>>(x, xthi, xtlo, Wq, Wk, Wv,
                                   wqh, wql, wkh, wkl, wvh, wvl);
  k_proj<<<dim3(64, 5, B_), 256, 0, stream>>>(wqh, wql, wkh, wkl, wvh, wvl,
                                              xthi, xtlo, bq, bk, bv,
                                              qhg, qlg, khg, klg, vg);
  k_flash<<<512, 256, 0, stream>>>(qhg, qlg, khg, klg, vg, Opart, mlpart);
  k_combine<<<256, 256, 0, stream>>>(Opart, mlpart, x, gamma, out);
}